// Round 11
// baseline (160.242 us; speedup 1.0000x reference)
//
#include <hip/hip_runtime.h>
#include <hip/hip_bf16.h>
#include <stdint.h>

typedef __bf16 bf16_t;
typedef bf16_t bf16x8 __attribute__((ext_vector_type(8)));
typedef float f32x4 __attribute__((ext_vector_type(4)));

#define BM 256
#define BN 256
#define BK 64

// ---------------------------------------------------------------------------
// async global->LDS 16B copy. LDS dest is wave-uniform base; HW adds lane*16.
// ---------------------------------------------------------------------------
__device__ __forceinline__ void gload_lds16(const void* g, void* l) {
  __builtin_amdgcn_global_load_lds(
      (const __attribute__((address_space(1))) uint32_t*)g,
      (__attribute__((address_space(3))) uint32_t*)l, 16, 0, 0);
}

// ---------------------------------------------------------------------------
// fused fp32->bf16 conversion: blocks [0,gx) convert x, [gx,..) convert
// weight (per-out-channel scale folded in). 8 elems/thread, grid-stride.
// Non-temporal fp32 loads: single-use streams must not evict the bf16
// working set from L2/L3 before the GEMM runs.
// ---------------------------------------------------------------------------
__global__ __launch_bounds__(256) void cvt_kernel(
    const float* __restrict__ x, bf16_t* __restrict__ xo, int n8x,
    const float* __restrict__ w, const float* __restrict__ scale,
    bf16_t* __restrict__ wo, int k8, int n8w, int gx) {
  if ((int)blockIdx.x < gx) {
    int stride = gx * blockDim.x;
    for (int i = blockIdx.x * blockDim.x + threadIdx.x; i < n8x; i += stride) {
      const f32x4* p = (const f32x4*)x + 2 * (size_t)i;
      f32x4 a = __builtin_nontemporal_load(p);
      f32x4 b = __builtin_nontemporal_load(p + 1);
      bf16x8 o;
#pragma unroll
      for (int r = 0; r < 4; ++r) { o[r] = (bf16_t)a[r]; o[r + 4] = (bf16_t)b[r]; }
      *((bf16x8*)xo + i) = o;
    }
  } else {
    int stride = (gridDim.x - gx) * blockDim.x;
    for (int i = (blockIdx.x - gx) * blockDim.x + threadIdx.x; i < n8w;
         i += stride) {
      int row = i / k8;
      float s = scale[row];
      const f32x4* p = (const f32x4*)w + 2 * (size_t)i;
      f32x4 a = __builtin_nontemporal_load(p);
      f32x4 b = __builtin_nontemporal_load(p + 1);
      bf16x8 o;
#pragma unroll
      for (int r = 0; r < 4; ++r) {
        o[r] = (bf16_t)(a[r] * s);
        o[r + 4] = (bf16_t)(b[r] * s);
      }
      *((bf16x8*)wo + i) = o;
    }
  }
}

// ---------------------------------------------------------------------------
// 256x256 bf16 GEMM, both K-major (B^T), 16x16x32 MFMA.
// K-loop = r9 (measured best line: 131.0 us, MfmaUtil 47.4, 0 conflicts):
// 4 phases/K-tile, 3 barriers/K-tile, cross-phase register prefetch,
// counted vmcnt(6)@P3 / vmcnt(4)@P4 (never 0 mid-loop). Hazard ledger in
// r9. Epilogue = r10 per-wave LDS transpose (WRITE_SIZE = 64MB ideal).
//
// r11 deltas (K-loop byte-identical):
//   - XCD swizzle: 2x16 slab -> 4x8 rectangle per XCD (working set
//     36MB -> 24MB per XCD; less L3 pressure).
//   - C stores non-temporal: C is write-once/read-never here; write-allocate
//     was evicting B panels from L2/L3 (FETCH 147.5MB vs 64MB ideal).
// ---------------------------------------------------------------------------
__global__ __launch_bounds__(512, 2) void gemm256(
    const bf16_t* __restrict__ A, const bf16_t* __restrict__ B,
    const float* __restrict__ bias, float* __restrict__ C,
    int M, int N, int K) {
  __shared__ __attribute__((aligned(16))) char lds[131072];

  const int tid = threadIdx.x;
  const int lane = tid & 63;
  const int wave = tid >> 6;
  const int wm = wave >> 2;   // 0..1  (row half of tile)
  const int wn = wave & 3;    // 0..3  (col quarter of tile)

  // XCD-aware swizzle: 4x8 tile-rectangle per XCD (bijective for 16x16 grid)
  const int ntn = N / BN;
  const int ntm = M / BM;
  int tm, tn;
  if (ntm == 16 && ntn == 16 && gridDim.x == 256) {
    int x = blockIdx.x & 7;          // XCD (dispatch round-robin)
    int loc = blockIdx.x >> 3;       // 0..31 within XCD
    tm = (x & 3) * 4 + (loc & 3);
    tn = (x >> 2) * 8 + (loc >> 2);
  } else {
    int nwg = gridDim.x;
    int wg = blockIdx.x;
    if ((nwg & 7) == 0) { int cpx = nwg >> 3; wg = (wg & 7) * cpx + (wg >> 3); }
    tm = wg / ntn;
    tn = wg % ntn;
  }

  const size_t Kb = (size_t)K * 2;
  const char* gApan = (const char*)A + (size_t)tm * BM * Kb;
  const char* gBpan = (const char*)B + (size_t)tn * BN * Kb;

  // ---- per-lane read bases (row*64 + swizzled 16B chunk) ----
  const int xc = (((lane >> 4) ^ ((lane >> 1) & 3)) << 4);
  const int aBase = (wm * 128 + (lane & 15)) * 64 + xc;  // + ch*4096 + i*1024
  const int bBase = (wn * 64 + (lane & 15)) * 64 + xc;   // + j*1024

  // ---- staging offsets: wave w covers rows [(2w+s)*16, +16) of a unit ----
  size_t srcoff[2];
  int ldst[2];
#pragma unroll
  for (int s = 0; s < 2; ++s) {
    int r = (wave * 2 + s) * 16 + (lane >> 2);
    int c = (lane & 3) ^ ((lane >> 3) & 3);
    srcoff[s] = (size_t)r * Kb + (size_t)(c << 4);
    ldst[s] = (wave * 2 + s) * 1024;
  }

#define STAGE_U(dstbase, pan, kbyte)                                          \
  {                                                                           \
    gload_lds16((pan) + srcoff[0] + (size_t)(kbyte), lds + (dstbase) + ldst[0]); \
    gload_lds16((pan) + srcoff[1] + (size_t)(kbyte), lds + (dstbase) + ldst[1]); \
  }
#define RD_A(dst, base, ch)                                                   \
  _Pragma("unroll") for (int i_ = 0; i_ < 4; ++i_)                            \
      dst[i_] = *(const bf16x8*)((base) + aoff[ch][i_]);
#define RD_B(dst, base)                                                       \
  _Pragma("unroll") for (int j_ = 0; j_ < 4; ++j_)                            \
      dst[j_] = *(const bf16x8*)((base) + boff[j_]);
#define MFMA16(ab, bb_, accbase)                                              \
  __builtin_amdgcn_s_setprio(1);                                              \
  _Pragma("unroll") for (int i_ = 0; i_ < 4; ++i_)                            \
      _Pragma("unroll") for (int j_ = 0; j_ < 4; ++j_)                        \
          acc[(accbase) + i_][j_] = __builtin_amdgcn_mfma_f32_16x16x32_bf16(  \
              ab[i_], bb_[j_], acc[(accbase) + i_][j_], 0, 0, 0);             \
  __builtin_amdgcn_s_setprio(0);
#define WAIT_LGKM(n) asm volatile("s_waitcnt lgkmcnt(" #n ")" ::: "memory")
#define WAIT_VM(n)   asm volatile("s_waitcnt vmcnt(" #n ")" ::: "memory")
#define BAR()        __builtin_amdgcn_s_barrier()

  // per-lane ds_read offsets
  int aoff[2][4], boff[4];
#pragma unroll
  for (int ch = 0; ch < 2; ++ch)
#pragma unroll
    for (int i = 0; i < 4; ++i) aoff[ch][i] = aBase + ch * 4096 + i * 1024;
#pragma unroll
  for (int j = 0; j < 4; ++j) boff[j] = bBase + j * 1024;

  f32x4 acc[8][4];
#pragma unroll
  for (int a = 0; a < 8; ++a)
#pragma unroll
    for (int j = 0; j < 4; ++j) acc[a][j] = (f32x4)0.0f;

  const int NT = K / BK;

  // ---- prologue: tile0 (4 units) + tile1 K0 (2 units); 2 left in flight ----
  STAGE_U(0,             gApan, 0);
  STAGE_U(32768,         gBpan, 0);
  STAGE_U(16384,         gApan, 64);
  STAGE_U(49152,         gBpan, 64);
  if (NT > 1) {
    STAGE_U(65536,         gApan, 128);
    STAGE_U(65536 + 32768, gBpan, 128);
    WAIT_VM(4);
  } else {
    WAIT_VM(0);
  }
  BAR();

  bf16x8 aX[4], aY[4], b0[4], b1[4];
  RD_A(aX, lds + 0, 0);       // A(ch0,K0) tile0
  RD_B(b0, lds + 32768);      // B-K0 tile0

  for (int t = 0; t < NT; ++t) {
    const int bb = (t & 1) << 16;
    const int nb = bb ^ 65536;
    const size_t kb1 = (size_t)(t + 1) * 128;
    const size_t kb2 = (size_t)(t + 2) * 128;
    const bool st1 = (t + 1) < NT;
    const bool st2 = (t + 2) < NT;

    const char* lA0 = lds + bb;
    const char* lA1 = lds + bb + 16384;
    const char* lB1 = lds + bb + 49152;

    // ---- P1: MFMA(aX=A ch0 K0, b0) ; prefetch aY = A ch1 K0 ----
    RD_A(aY, lA0, 1);
    if (st1) STAGE_U(nb + 16384, gApan, kb1 + 64);   // A-K1(t+1)
    WAIT_LGKM(4);
    MFMA16(aX, b0, 0);
    BAR();   // KEEP: separates P4(t-1) prefetch-reads from P3/P4(t) stages

    // ---- P2: MFMA(aY, b0) ; prefetch aX = A ch0 K1, b1 = B-K1 ----
    RD_A(aX, lA1, 0);
    RD_B(b1, lB1);
    if (st1) STAGE_U(nb + 49152, gBpan, kb1 + 64);   // B-K1(t+1)
    WAIT_LGKM(8);
    MFMA16(aY, b0, 4);
    // (end-P2 barrier deleted — r9 ledger)

    // ---- P3: MFMA(aX, b1) ; prefetch aY = A ch1 K1 ----
    RD_A(aY, lA1, 1);
    if (st2) STAGE_U(bb, gApan, kb2);                // A-K0(t+2)
    WAIT_LGKM(4);
    MFMA16(aX, b1, 0);
    WAIT_VM(6);   // drains A/B-K0(t+1)
    BAR();   // KEEP: publishes the vmcnt(6) drain

    // ---- P4: MFMA(aY, b1) ; prefetch next tile's aX, b0 ----
    if (st1) {
      RD_A(aX, lds + nb, 0);        // A(ch0,K0) of t+1
      RD_B(b0, lds + nb + 32768);   // B-K0 of t+1
    }
    if (st2) STAGE_U(bb + 32768, gBpan, kb2);        // B-K0(t+2)
    if (st1) { WAIT_LGKM(8); } else { WAIT_LGKM(0); }
    MFMA16(aY, b1, 4);
    WAIT_VM(4);   // drains A/B-K1(t+1)
    BAR();   // KEEP: publishes the vmcnt(4) drain
  }
#undef STAGE_U
#undef RD_A
#undef RD_B
#undef MFMA16
#undef BAR

  // ---- epilogue: per-wave LDS transpose -> coalesced NT dwordx4 stores ----
  {
    float* wlds = (float*)(lds + wave * 16384);
    const int hi4 = lane >> 4;      // 0..3
    const int lo = lane & 15;
    const int row0 = tm * BM + wm * 128;
    const int col0 = tn * BN + wn * 64;
    float bv[4];
#pragma unroll
    for (int j = 0; j < 4; ++j) bv[j] = bias[col0 + j * 16 + lo];

#pragma unroll
    for (int ch = 0; ch < 2; ++ch) {
#pragma unroll
      for (int i = 0; i < 4; ++i) {
#pragma unroll
        for (int j = 0; j < 4; ++j) {
#pragma unroll
          for (int r = 0; r < 4; ++r) {
            int row = i * 16 + hi4 * 4 + r;
            int colx = (j * 16 + lo) ^ ((hi4 & 1) << 2) ^ ((hi4 & 2) << 3);
            wlds[row * 64 + colx] = acc[ch * 4 + i][j][r] + bv[j];
          }
        }
      }
      WAIT_LGKM(0);   // own-wave ds_write -> ds_read ordering
#pragma unroll
      for (int s = 0; s < 16; ++s) {
        int rr = s * 4 + hi4;
        int c4 = lo ^ (s & 1) ^ (((s >> 1) & 1) << 2);
        f32x4 v = *(const f32x4*)(wlds + rr * 64 + c4 * 4);
        float* gp = &C[(size_t)(row0 + ch * 64 + rr) * N + col0 + lo * 4];
        __builtin_nontemporal_store(v, (f32x4*)gp);
      }
    }
  }
#undef WAIT_LGKM
#undef WAIT_VM
}

// ---------------------------------------------------------------------------
// fallback: naive fp32 (only if workspace/shape unsuitable — correctness net)
// ---------------------------------------------------------------------------
__global__ void fallback_gemm(const float* __restrict__ x,
                              const float* __restrict__ w,
                              const float* __restrict__ s,
                              const float* __restrict__ b,
                              float* __restrict__ out, int M, int N, int K) {
  int o = blockIdx.x * blockDim.x + threadIdx.x;
  if (o >= M * N) return;
  int m = o / N, n = o % N;
  const float* xr = x + (size_t)m * K;
  const float* wr = w + (size_t)n * K;
  float acc = 0.f;
  for (int k = 0; k < K; ++k) acc += xr[k] * wr[k];
  out[o] = acc * s[n] + b[n];
}

extern "C" void kernel_launch(void* const* d_in, const int* in_sizes, int n_in,
                              void* d_out, int out_size, void* d_ws,
                              size_t ws_size, hipStream_t stream) {
  const float* x = (const float*)d_in[0];
  const float* w = (const float*)d_in[1];
  const float* sc = (const float*)d_in[2];
  const float* bias = (const float*)d_in[3];
  float* out = (float*)d_out;

  const int N = in_sizes[2];        // out_features (weight_scale length)
  const int K = in_sizes[1] / N;    // in_features
  const int M = in_sizes[0] / K;    // tokens

  const size_t need = ((size_t)M * K + (size_t)N * K) * sizeof(bf16_t);
  const bool fast = (ws_size >= need) && (M % BM == 0) && (N % BN == 0) &&
                    (K % BK == 0) && (N % 4 == 0) && (K / BK >= 1);

  if (fast) {
    bf16_t* xb = (bf16_t*)d_ws;
    bf16_t* wb = xb + (size_t)M * K;

    int n8x = (M * K) / 8;
    int n8w = (N * K) / 8;
    const int gx = 2048;
    cvt_kernel<<<gx + 2048, 256, 0, stream>>>(x, xb, n8x, w, sc, wb, K / 8,
                                              n8w, gx);

    dim3 grid((M / BM) * (N / BN));
    gemm256<<<grid, 512, 0, stream>>>(xb, wb, bias, out, M, N, K);
  } else {
    int total = M * N;
    fallback_gemm<<<(total + 255) / 256, 256, 0, stream>>>(x, w, sc, bias, out,
                                                           M, N, K);
  }
}

// Round 12
// 154.505 us; speedup vs baseline: 1.0371x; 1.0371x over previous
//
#include <hip/hip_runtime.h>
#include <hip/hip_bf16.h>
#include <stdint.h>

typedef __bf16 bf16_t;
typedef bf16_t bf16x8 __attribute__((ext_vector_type(8)));
typedef float f32x4 __attribute__((ext_vector_type(4)));

#define BM 256
#define BN 256
#define BK 64

// ---------------------------------------------------------------------------
// async global->LDS 16B copy. LDS dest is wave-uniform base; HW adds lane*16.
// ---------------------------------------------------------------------------
__device__ __forceinline__ void gload_lds16(const void* g, void* l) {
  __builtin_amdgcn_global_load_lds(
      (const __attribute__((address_space(1))) uint32_t*)g,
      (__attribute__((address_space(3))) uint32_t*)l, 16, 0, 0);
}

// ---------------------------------------------------------------------------
// fused fp32->bf16 conversion: blocks [0,gx) convert x, [gx,..) convert
// weight (per-out-channel scale folded in). 8 elems/thread, grid-stride.
// REGULAR loads (r11 lesson: NT loads bypass L3 where the fp32 inputs are
// resident across replays -> +9us cvt; NT is only right for the C stores).
// ---------------------------------------------------------------------------
__global__ __launch_bounds__(256) void cvt_kernel(
    const float* __restrict__ x, bf16_t* __restrict__ xo, int n8x,
    const float* __restrict__ w, const float* __restrict__ scale,
    bf16_t* __restrict__ wo, int k8, int n8w, int gx) {
  if ((int)blockIdx.x < gx) {
    int stride = gx * blockDim.x;
    for (int i = blockIdx.x * blockDim.x + threadIdx.x; i < n8x; i += stride) {
      const f32x4* p = (const f32x4*)x + 2 * (size_t)i;
      f32x4 a = p[0], b = p[1];
      bf16x8 o;
#pragma unroll
      for (int r = 0; r < 4; ++r) { o[r] = (bf16_t)a[r]; o[r + 4] = (bf16_t)b[r]; }
      *((bf16x8*)xo + i) = o;
    }
  } else {
    int stride = (gridDim.x - gx) * blockDim.x;
    for (int i = (blockIdx.x - gx) * blockDim.x + threadIdx.x; i < n8w;
         i += stride) {
      int row = i / k8;
      float s = scale[row];
      const f32x4* p = (const f32x4*)w + 2 * (size_t)i;
      f32x4 a = p[0], b = p[1];
      bf16x8 o;
#pragma unroll
      for (int r = 0; r < 4; ++r) {
        o[r] = (bf16_t)(a[r] * s);
        o[r + 4] = (bf16_t)(b[r] * s);
      }
      *((bf16x8*)wo + i) = o;
    }
  }
}

// ---------------------------------------------------------------------------
// 256x256 bf16 GEMM, both K-major (B^T), 16x16x32 MFMA.
// K-loop = r9 (4 phases/K-tile, 3 barriers/K-tile, cross-phase register
// prefetch, counted vmcnt(6)@P3 / vmcnt(4)@P4 — hazard ledger in r9).
// Epilogue = r10 per-wave LDS transpose + r11 non-temporal C stores
// (WRITE 65.6MB ~ ideal; FETCH 147.5 -> 98.4MB). XCD swizzle = r11 4x8
// rectangles. Measured: GEMM 129.5us, MfmaUtil 47.5, conflicts ~5e5 (free
// 2-way epilogue aliasing).
// ---------------------------------------------------------------------------
__global__ __launch_bounds__(512, 2) void gemm256(
    const bf16_t* __restrict__ A, const bf16_t* __restrict__ B,
    const float* __restrict__ bias, float* __restrict__ C,
    int M, int N, int K) {
  __shared__ __attribute__((aligned(16))) char lds[131072];

  const int tid = threadIdx.x;
  const int lane = tid & 63;
  const int wave = tid >> 6;
  const int wm = wave >> 2;   // 0..1  (row half of tile)
  const int wn = wave & 3;    // 0..3  (col quarter of tile)

  // XCD-aware swizzle: 4x8 tile-rectangle per XCD (bijective for 16x16 grid)
  const int ntn = N / BN;
  const int ntm = M / BM;
  int tm, tn;
  if (ntm == 16 && ntn == 16 && gridDim.x == 256) {
    int x = blockIdx.x & 7;          // XCD (dispatch round-robin)
    int loc = blockIdx.x >> 3;       // 0..31 within XCD
    tm = (x & 3) * 4 + (loc & 3);
    tn = (x >> 2) * 8 + (loc >> 2);
  } else {
    int nwg = gridDim.x;
    int wg = blockIdx.x;
    if ((nwg & 7) == 0) { int cpx = nwg >> 3; wg = (wg & 7) * cpx + (wg >> 3); }
    tm = wg / ntn;
    tn = wg % ntn;
  }

  const size_t Kb = (size_t)K * 2;
  const char* gApan = (const char*)A + (size_t)tm * BM * Kb;
  const char* gBpan = (const char*)B + (size_t)tn * BN * Kb;

  // ---- per-lane read bases (row*64 + swizzled 16B chunk) ----
  const int xc = (((lane >> 4) ^ ((lane >> 1) & 3)) << 4);
  const int aBase = (wm * 128 + (lane & 15)) * 64 + xc;  // + ch*4096 + i*1024
  const int bBase = (wn * 64 + (lane & 15)) * 64 + xc;   // + j*1024

  // ---- staging offsets: wave w covers rows [(2w+s)*16, +16) of a unit ----
  size_t srcoff[2];
  int ldst[2];
#pragma unroll
  for (int s = 0; s < 2; ++s) {
    int r = (wave * 2 + s) * 16 + (lane >> 2);
    int c = (lane & 3) ^ ((lane >> 3) & 3);
    srcoff[s] = (size_t)r * Kb + (size_t)(c << 4);
    ldst[s] = (wave * 2 + s) * 1024;
  }

#define STAGE_U(dstbase, pan, kbyte)                                          \
  {                                                                           \
    gload_lds16((pan) + srcoff[0] + (size_t)(kbyte), lds + (dstbase) + ldst[0]); \
    gload_lds16((pan) + srcoff[1] + (size_t)(kbyte), lds + (dstbase) + ldst[1]); \
  }
#define RD_A(dst, base, ch)                                                   \
  _Pragma("unroll") for (int i_ = 0; i_ < 4; ++i_)                            \
      dst[i_] = *(const bf16x8*)((base) + aoff[ch][i_]);
#define RD_B(dst, base)                                                       \
  _Pragma("unroll") for (int j_ = 0; j_ < 4; ++j_)                            \
      dst[j_] = *(const bf16x8*)((base) + boff[j_]);
#define MFMA16(ab, bb_, accbase)                                              \
  __builtin_amdgcn_s_setprio(1);                                              \
  _Pragma("unroll") for (int i_ = 0; i_ < 4; ++i_)                            \
      _Pragma("unroll") for (int j_ = 0; j_ < 4; ++j_)                        \
          acc[(accbase) + i_][j_] = __builtin_amdgcn_mfma_f32_16x16x32_bf16(  \
              ab[i_], bb_[j_], acc[(accbase) + i_][j_], 0, 0, 0);             \
  __builtin_amdgcn_s_setprio(0);
#define WAIT_LGKM(n) asm volatile("s_waitcnt lgkmcnt(" #n ")" ::: "memory")
#define WAIT_VM(n)   asm volatile("s_waitcnt vmcnt(" #n ")" ::: "memory")
#define BAR()        __builtin_amdgcn_s_barrier()

  // per-lane ds_read offsets
  int aoff[2][4], boff[4];
#pragma unroll
  for (int ch = 0; ch < 2; ++ch)
#pragma unroll
    for (int i = 0; i < 4; ++i) aoff[ch][i] = aBase + ch * 4096 + i * 1024;
#pragma unroll
  for (int j = 0; j < 4; ++j) boff[j] = bBase + j * 1024;

  f32x4 acc[8][4];
#pragma unroll
  for (int a = 0; a < 8; ++a)
#pragma unroll
    for (int j = 0; j < 4; ++j) acc[a][j] = (f32x4)0.0f;

  const int NT = K / BK;

  // ---- prologue: tile0 (4 units) + tile1 K0 (2 units); 2 left in flight ----
  STAGE_U(0,             gApan, 0);
  STAGE_U(32768,         gBpan, 0);
  STAGE_U(16384,         gApan, 64);
  STAGE_U(49152,         gBpan, 64);
  if (NT > 1) {
    STAGE_U(65536,         gApan, 128);
    STAGE_U(65536 + 32768, gBpan, 128);
    WAIT_VM(4);
  } else {
    WAIT_VM(0);
  }
  BAR();

  bf16x8 aX[4], aY[4], b0[4], b1[4];
  RD_A(aX, lds + 0, 0);       // A(ch0,K0) tile0
  RD_B(b0, lds + 32768);      // B-K0 tile0

  for (int t = 0; t < NT; ++t) {
    const int bb = (t & 1) << 16;
    const int nb = bb ^ 65536;
    const size_t kb1 = (size_t)(t + 1) * 128;
    const size_t kb2 = (size_t)(t + 2) * 128;
    const bool st1 = (t + 1) < NT;
    const bool st2 = (t + 2) < NT;

    const char* lA0 = lds + bb;
    const char* lA1 = lds + bb + 16384;
    const char* lB1 = lds + bb + 49152;

    // ---- P1: MFMA(aX=A ch0 K0, b0) ; prefetch aY = A ch1 K0 ----
    RD_A(aY, lA0, 1);
    if (st1) STAGE_U(nb + 16384, gApan, kb1 + 64);   // A-K1(t+1)
    WAIT_LGKM(4);
    MFMA16(aX, b0, 0);
    BAR();   // KEEP: separates P4(t-1) prefetch-reads from P3/P4(t) stages

    // ---- P2: MFMA(aY, b0) ; prefetch aX = A ch0 K1, b1 = B-K1 ----
    RD_A(aX, lA1, 0);
    RD_B(b1, lB1);
    if (st1) STAGE_U(nb + 49152, gBpan, kb1 + 64);   // B-K1(t+1)
    WAIT_LGKM(8);
    MFMA16(aY, b0, 4);
    // (end-P2 barrier deleted — r9 ledger)

    // ---- P3: MFMA(aX, b1) ; prefetch aY = A ch1 K1 ----
    RD_A(aY, lA1, 1);
    if (st2) STAGE_U(bb, gApan, kb2);                // A-K0(t+2)
    WAIT_LGKM(4);
    MFMA16(aX, b1, 0);
    WAIT_VM(6);   // drains A/B-K0(t+1)
    BAR();   // KEEP: publishes the vmcnt(6) drain

    // ---- P4: MFMA(aY, b1) ; prefetch next tile's aX, b0 ----
    if (st1) {
      RD_A(aX, lds + nb, 0);        // A(ch0,K0) of t+1
      RD_B(b0, lds + nb + 32768);   // B-K0 of t+1
    }
    if (st2) STAGE_U(bb + 32768, gBpan, kb2);        // B-K0(t+2)
    if (st1) { WAIT_LGKM(8); } else { WAIT_LGKM(0); }
    MFMA16(aY, b1, 4);
    WAIT_VM(4);   // drains A/B-K1(t+1)
    BAR();   // KEEP: publishes the vmcnt(4) drain
  }
#undef STAGE_U
#undef RD_A
#undef RD_B
#undef MFMA16
#undef BAR

  // ---- epilogue: per-wave LDS transpose -> coalesced NT dwordx4 stores ----
  {
    float* wlds = (float*)(lds + wave * 16384);
    const int hi4 = lane >> 4;      // 0..3
    const int lo = lane & 15;
    const int row0 = tm * BM + wm * 128;
    const int col0 = tn * BN + wn * 64;
    float bv[4];
#pragma unroll
    for (int j = 0; j < 4; ++j) bv[j] = bias[col0 + j * 16 + lo];

#pragma unroll
    for (int ch = 0; ch < 2; ++ch) {
#pragma unroll
      for (int i = 0; i < 4; ++i) {
#pragma unroll
        for (int j = 0; j < 4; ++j) {
#pragma unroll
          for (int r = 0; r < 4; ++r) {
            int row = i * 16 + hi4 * 4 + r;
            int colx = (j * 16 + lo) ^ ((hi4 & 1) << 2) ^ ((hi4 & 2) << 3);
            wlds[row * 64 + colx] = acc[ch * 4 + i][j][r] + bv[j];
          }
        }
      }
      WAIT_LGKM(0);   // own-wave ds_write -> ds_read ordering
#pragma unroll
      for (int s = 0; s < 16; ++s) {
        int rr = s * 4 + hi4;
        int c4 = lo ^ (s & 1) ^ (((s >> 1) & 1) << 2);
        f32x4 v = *(const f32x4*)(wlds + rr * 64 + c4 * 4);
        float* gp = &C[(size_t)(row0 + ch * 64 + rr) * N + col0 + lo * 4];
        __builtin_nontemporal_store(v, (f32x4*)gp);
      }
    }
  }
#undef WAIT_LGKM
#undef WAIT_VM
}

// ---------------------------------------------------------------------------
// fallback: naive fp32 (only if workspace/shape unsuitable — correctness net)
// ---------------------------------------------------------------------------
__global__ void fallback_gemm(const float* __restrict__ x,
                              const float* __restrict__ w,
                              const float* __restrict__ s,
                              const float* __restrict__ b,
                              float* __restrict__ out, int M, int N, int K) {
  int o = blockIdx.x * blockDim.x + threadIdx.x;
  if (o >= M * N) return;
  int m = o / N, n = o % N;
  const float* xr = x + (size_t)m * K;
  const float* wr = w + (size_t)n * K;
  float acc = 0.f;
  for (int k = 0; k < K; ++k) acc += xr[k] * wr[k];
  out[o] = acc * s[n] + b[n];
}

extern "C" void kernel_launch(void* const* d_in, const int* in_sizes, int n_in,
                              void* d_out, int out_size, void* d_ws,
                              size_t ws_size, hipStream_t stream) {
  const float* x = (const float*)d_in[0];
  const float* w = (const float*)d_in[1];
  const float* sc = (const float*)d_in[2];
  const float* bias = (const float*)d_in[3];
  float* out = (float*)d_out;

  const int N = in_sizes[2];        // out_features (weight_scale length)
  const int K = in_sizes[1] / N;    // in_features
  const int M = in_sizes[0] / K;    // tokens

  const size_t need = ((size_t)M * K + (size_t)N * K) * sizeof(bf16_t);
  const bool fast = (ws_size >= need) && (M % BM == 0) && (N % BN == 0) &&
                    (K % BK == 0) && (N % 4 == 0) && (K / BK >= 1);

  if (fast) {
    bf16_t* xb = (bf16_t*)d_ws;
    bf16_t* wb = xb + (size_t)M * K;

    int n8x = (M * K) / 8;
    int n8w = (N * K) / 8;
    const int gx = 2048;
    cvt_kernel<<<gx + 2048, 256, 0, stream>>>(x, xb, n8x, w, sc, wb, K / 8,
                                              n8w, gx);

    dim3 grid((M / BM) * (N / BN));
    gemm256<<<grid, 512, 0, stream>>>(xb, wb, bias, out, M, N, K);
  } else {
    int total = M * N;
    fallback_gemm<<<(total + 255) / 256, 256, 0, stream>>>(x, w, sc, bias, out,
                                                           M, N, K);
  }
}

// Round 13
// 153.230 us; speedup vs baseline: 1.0458x; 1.0083x over previous
//
#include <hip/hip_runtime.h>
#include <hip/hip_bf16.h>
#include <stdint.h>

typedef __bf16 bf16_t;
typedef bf16_t bf16x8 __attribute__((ext_vector_type(8)));
typedef float f32x4 __attribute__((ext_vector_type(4)));

#define BM 256
#define BN 256
#define BK 64

// ---------------------------------------------------------------------------
// async global->LDS 16B copy. LDS dest is wave-uniform base; HW adds lane*16.
// ---------------------------------------------------------------------------
__device__ __forceinline__ void gload_lds16(const void* g, void* l) {
  __builtin_amdgcn_global_load_lds(
      (const __attribute__((address_space(1))) uint32_t*)g,
      (__attribute__((address_space(3))) uint32_t*)l, 16, 0, 0);
}

// ---------------------------------------------------------------------------
// fused fp32->bf16 conversion: blocks [0,gx) convert x, [gx,..) convert
// weight (per-out-channel scale folded in). 8 elems/thread, grid-stride.
// REGULAR loads (r11 lesson: NT loads bypass the L3 the inputs live in).
// ---------------------------------------------------------------------------
__global__ __launch_bounds__(256) void cvt_kernel(
    const float* __restrict__ x, bf16_t* __restrict__ xo, int n8x,
    const float* __restrict__ w, const float* __restrict__ scale,
    bf16_t* __restrict__ wo, int k8, int n8w, int gx) {
  if ((int)blockIdx.x < gx) {
    int stride = gx * blockDim.x;
    for (int i = blockIdx.x * blockDim.x + threadIdx.x; i < n8x; i += stride) {
      const f32x4* p = (const f32x4*)x + 2 * (size_t)i;
      f32x4 a = p[0], b = p[1];
      bf16x8 o;
#pragma unroll
      for (int r = 0; r < 4; ++r) { o[r] = (bf16_t)a[r]; o[r + 4] = (bf16_t)b[r]; }
      *((bf16x8*)xo + i) = o;
    }
  } else {
    int stride = (gridDim.x - gx) * blockDim.x;
    for (int i = (blockIdx.x - gx) * blockDim.x + threadIdx.x; i < n8w;
         i += stride) {
      int row = i / k8;
      float s = scale[row];
      const f32x4* p = (const f32x4*)w + 2 * (size_t)i;
      f32x4 a = p[0], b = p[1];
      bf16x8 o;
#pragma unroll
      for (int r = 0; r < 4; ++r) {
        o[r] = (bf16_t)(a[r] * s);
        o[r + 4] = (bf16_t)(b[r] * s);
      }
      *((bf16x8*)wo + i) = o;
    }
  }
}

// ---------------------------------------------------------------------------
// 256x256 bf16 GEMM, both K-major (B^T), 16x16x32 MFMA.
// K-loop = r9 barriers/vm-waits (hazard ledger in r9), r12 delta:
//   - coarse per-phase lgkm waits REMOVED: the compiler's per-use
//     fine-grained lgkmcnt lets the first MFMA issue as soon as its own
//     operands land (FIFO), instead of draining the whole phase's reads.
//   - P2/P4 issue RD_B before RD_A so B (needed by all 16 MFMA) lands
//     first and A-frags stream in issue order.
// Barriers + counted vmcnt(6)@P3 / vmcnt(4)@P4 unchanged (memory ops can't
// cross them; MFMA hoisting above a barrier is data-dep-safe here).
// Epilogue = r10 per-wave LDS transpose + NT C stores. XCD swizzle = r11.
// Measured baseline for this round: GEMM ~130.6us, MfmaUtil 47.5.
// ---------------------------------------------------------------------------
__global__ __launch_bounds__(512, 2) void gemm256(
    const bf16_t* __restrict__ A, const bf16_t* __restrict__ B,
    const float* __restrict__ bias, float* __restrict__ C,
    int M, int N, int K) {
  __shared__ __attribute__((aligned(16))) char lds[131072];

  const int tid = threadIdx.x;
  const int lane = tid & 63;
  const int wave = tid >> 6;
  const int wm = wave >> 2;   // 0..1  (row half of tile)
  const int wn = wave & 3;    // 0..3  (col quarter of tile)

  // XCD-aware swizzle: 4x8 tile-rectangle per XCD (bijective for 16x16 grid)
  const int ntn = N / BN;
  const int ntm = M / BM;
  int tm, tn;
  if (ntm == 16 && ntn == 16 && gridDim.x == 256) {
    int x = blockIdx.x & 7;          // XCD (dispatch round-robin)
    int loc = blockIdx.x >> 3;       // 0..31 within XCD
    tm = (x & 3) * 4 + (loc & 3);
    tn = (x >> 2) * 8 + (loc >> 2);
  } else {
    int nwg = gridDim.x;
    int wg = blockIdx.x;
    if ((nwg & 7) == 0) { int cpx = nwg >> 3; wg = (wg & 7) * cpx + (wg >> 3); }
    tm = wg / ntn;
    tn = wg % ntn;
  }

  const size_t Kb = (size_t)K * 2;
  const char* gApan = (const char*)A + (size_t)tm * BM * Kb;
  const char* gBpan = (const char*)B + (size_t)tn * BN * Kb;

  // ---- per-lane read bases (row*64 + swizzled 16B chunk) ----
  const int xc = (((lane >> 4) ^ ((lane >> 1) & 3)) << 4);
  const int aBase = (wm * 128 + (lane & 15)) * 64 + xc;  // + ch*4096 + i*1024
  const int bBase = (wn * 64 + (lane & 15)) * 64 + xc;   // + j*1024

  // ---- staging offsets: wave w covers rows [(2w+s)*16, +16) of a unit ----
  size_t srcoff[2];
  int ldst[2];
#pragma unroll
  for (int s = 0; s < 2; ++s) {
    int r = (wave * 2 + s) * 16 + (lane >> 2);
    int c = (lane & 3) ^ ((lane >> 3) & 3);
    srcoff[s] = (size_t)r * Kb + (size_t)(c << 4);
    ldst[s] = (wave * 2 + s) * 1024;
  }

#define STAGE_U(dstbase, pan, kbyte)                                          \
  {                                                                           \
    gload_lds16((pan) + srcoff[0] + (size_t)(kbyte), lds + (dstbase) + ldst[0]); \
    gload_lds16((pan) + srcoff[1] + (size_t)(kbyte), lds + (dstbase) + ldst[1]); \
  }
#define RD_A(dst, base, ch)                                                   \
  _Pragma("unroll") for (int i_ = 0; i_ < 4; ++i_)                            \
      dst[i_] = *(const bf16x8*)((base) + aoff[ch][i_]);
#define RD_B(dst, base)                                                       \
  _Pragma("unroll") for (int j_ = 0; j_ < 4; ++j_)                            \
      dst[j_] = *(const bf16x8*)((base) + boff[j_]);
#define MFMA16(ab, bb_, accbase)                                              \
  __builtin_amdgcn_s_setprio(1);                                              \
  _Pragma("unroll") for (int i_ = 0; i_ < 4; ++i_)                            \
      _Pragma("unroll") for (int j_ = 0; j_ < 4; ++j_)                        \
          acc[(accbase) + i_][j_] = __builtin_amdgcn_mfma_f32_16x16x32_bf16(  \
              ab[i_], bb_[j_], acc[(accbase) + i_][j_], 0, 0, 0);             \
  __builtin_amdgcn_s_setprio(0);
#define WAIT_LGKM(n) asm volatile("s_waitcnt lgkmcnt(" #n ")" ::: "memory")
#define WAIT_VM(n)   asm volatile("s_waitcnt vmcnt(" #n ")" ::: "memory")
#define BAR()        __builtin_amdgcn_s_barrier()

  // per-lane ds_read offsets
  int aoff[2][4], boff[4];
#pragma unroll
  for (int ch = 0; ch < 2; ++ch)
#pragma unroll
    for (int i = 0; i < 4; ++i) aoff[ch][i] = aBase + ch * 4096 + i * 1024;
#pragma unroll
  for (int j = 0; j < 4; ++j) boff[j] = bBase + j * 1024;

  f32x4 acc[8][4];
#pragma unroll
  for (int a = 0; a < 8; ++a)
#pragma unroll
    for (int j = 0; j < 4; ++j) acc[a][j] = (f32x4)0.0f;

  const int NT = K / BK;

  // ---- prologue: tile0 (4 units) + tile1 K0 (2 units); 2 left in flight ----
  STAGE_U(0,             gApan, 0);
  STAGE_U(32768,         gBpan, 0);
  STAGE_U(16384,         gApan, 64);
  STAGE_U(49152,         gBpan, 64);
  if (NT > 1) {
    STAGE_U(65536,         gApan, 128);
    STAGE_U(65536 + 32768, gBpan, 128);
    WAIT_VM(4);
  } else {
    WAIT_VM(0);
  }
  BAR();

  bf16x8 aX[4], aY[4], b0[4], b1[4];
  RD_B(b0, lds + 32768);      // B-K0 tile0 (B first)
  RD_A(aX, lds + 0, 0);       // A(ch0,K0) tile0

  for (int t = 0; t < NT; ++t) {
    const int bb = (t & 1) << 16;
    const int nb = bb ^ 65536;
    const size_t kb1 = (size_t)(t + 1) * 128;
    const size_t kb2 = (size_t)(t + 2) * 128;
    const bool st1 = (t + 1) < NT;
    const bool st2 = (t + 2) < NT;

    const char* lA0 = lds + bb;
    const char* lA1 = lds + bb + 16384;
    const char* lB1 = lds + bb + 49152;

    // ---- P1: MFMA(aX=A ch0 K0, b0) ; prefetch aY = A ch1 K0 ----
    RD_A(aY, lA0, 1);
    if (st1) STAGE_U(nb + 16384, gApan, kb1 + 64);   // A-K1(t+1)
    MFMA16(aX, b0, 0);          // compiler emits per-use lgkmcnt for aX/b0
    BAR();   // KEEP: separates P4(t-1) prefetch-reads from P3/P4(t) stages

    // ---- P2: MFMA(aY, b0) ; prefetch b1 = B-K1 first, then aX = A ch0 K1 --
    RD_B(b1, lB1);
    RD_A(aX, lA1, 0);
    if (st1) STAGE_U(nb + 49152, gBpan, kb1 + 64);   // B-K1(t+1)
    MFMA16(aY, b0, 4);          // per-use waits drain only aY
    // (end-P2 barrier deleted — r9 ledger)

    // ---- P3: MFMA(aX, b1) ; prefetch aY = A ch1 K1 ----
    RD_A(aY, lA1, 1);
    if (st2) STAGE_U(bb, gApan, kb2);                // A-K0(t+2)
    MFMA16(aX, b1, 0);
    WAIT_VM(6);   // drains A/B-K0(t+1)
    BAR();   // KEEP: publishes the vmcnt(6) drain

    // ---- P4: MFMA(aY, b1) ; prefetch next tile's b0 then aX ----
    if (st1) {
      RD_B(b0, lds + nb + 32768);   // B-K0 of t+1 (B first)
      RD_A(aX, lds + nb, 0);        // A(ch0,K0) of t+1
    }
    if (st2) STAGE_U(bb + 32768, gBpan, kb2);        // B-K0(t+2)
    MFMA16(aY, b1, 4);
    WAIT_VM(4);   // drains A/B-K1(t+1)
    BAR();   // KEEP: publishes the vmcnt(4) drain
  }
#undef STAGE_U
#undef RD_A
#undef RD_B
#undef MFMA16
#undef BAR

  // ---- epilogue: per-wave LDS transpose -> coalesced NT dwordx4 stores ----
  {
    float* wlds = (float*)(lds + wave * 16384);
    const int hi4 = lane >> 4;      // 0..3
    const int lo = lane & 15;
    const int row0 = tm * BM + wm * 128;
    const int col0 = tn * BN + wn * 64;
    float bv[4];
#pragma unroll
    for (int j = 0; j < 4; ++j) bv[j] = bias[col0 + j * 16 + lo];

#pragma unroll
    for (int ch = 0; ch < 2; ++ch) {
#pragma unroll
      for (int i = 0; i < 4; ++i) {
#pragma unroll
        for (int j = 0; j < 4; ++j) {
#pragma unroll
          for (int r = 0; r < 4; ++r) {
            int row = i * 16 + hi4 * 4 + r;
            int colx = (j * 16 + lo) ^ ((hi4 & 1) << 2) ^ ((hi4 & 2) << 3);
            wlds[row * 64 + colx] = acc[ch * 4 + i][j][r] + bv[j];
          }
        }
      }
      WAIT_LGKM(0);   // own-wave ds_write -> ds_read ordering
#pragma unroll
      for (int s = 0; s < 16; ++s) {
        int rr = s * 4 + hi4;
        int c4 = lo ^ (s & 1) ^ (((s >> 1) & 1) << 2);
        f32x4 v = *(const f32x4*)(wlds + rr * 64 + c4 * 4);
        float* gp = &C[(size_t)(row0 + ch * 64 + rr) * N + col0 + lo * 4];
        __builtin_nontemporal_store(v, (f32x4*)gp);
      }
    }
  }
#undef WAIT_LGKM
#undef WAIT_VM
}

// ---------------------------------------------------------------------------
// fallback: naive fp32 (only if workspace/shape unsuitable — correctness net)
// ---------------------------------------------------------------------------
__global__ void fallback_gemm(const float* __restrict__ x,
                              const float* __restrict__ w,
                              const float* __restrict__ s,
                              const float* __restrict__ b,
                              float* __restrict__ out, int M, int N, int K) {
  int o = blockIdx.x * blockDim.x + threadIdx.x;
  if (o >= M * N) return;
  int m = o / N, n = o % N;
  const float* xr = x + (size_t)m * K;
  const float* wr = w + (size_t)n * K;
  float acc = 0.f;
  for (int k = 0; k < K; ++k) acc += xr[k] * wr[k];
  out[o] = acc * s[n] + b[n];
}

extern "C" void kernel_launch(void* const* d_in, const int* in_sizes, int n_in,
                              void* d_out, int out_size, void* d_ws,
                              size_t ws_size, hipStream_t stream) {
  const float* x = (const float*)d_in[0];
  const float* w = (const float*)d_in[1];
  const float* sc = (const float*)d_in[2];
  const float* bias = (const float*)d_in[3];
  float* out = (float*)d_out;

  const int N = in_sizes[2];        // out_features (weight_scale length)
  const int K = in_sizes[1] / N;    // in_features
  const int M = in_sizes[0] / K;    // tokens

  const size_t need = ((size_t)M * K + (size_t)N * K) * sizeof(bf16_t);
  const bool fast = (ws_size >= need) && (M % BM == 0) && (N % BN == 0) &&
                    (K % BK == 0) && (N % 4 == 0) && (K / BK >= 1);

  if (fast) {
    bf16_t* xb = (bf16_t*)d_ws;
    bf16_t* wb = xb + (size_t)M * K;

    int n8x = (M * K) / 8;
    int n8w = (N * K) / 8;
    const int gx = 2048;
    cvt_kernel<<<gx + 2048, 256, 0, stream>>>(x, xb, n8x, w, sc, wb, K / 8,
                                              n8w, gx);

    dim3 grid((M / BM) * (N / BN));
    gemm256<<<grid, 512, 0, stream>>>(xb, wb, bias, out, M, N, K);
  } else {
    int total = M * N;
    fallback_gemm<<<(total + 255) / 256, 256, 0, stream>>>(x, w, sc, bias, out,
                                                           M, N, K);
  }
}